// Round 10
// baseline (54694.287 us; speedup 1.0000x reference)
//
#include <hip/hip_runtime.h>

// ---------------------------------------------------------------------------
// Dual-GRU + per-step dot-attention "counterfactual" model, fp32.
// R10: two orthogonal fixes on the R9 post-mortem (115us/step, VALUBusy 20%):
//  1) LLC-mailbox sync: cross-WG state (FHX/CFHX, FOLD/CFOLD, CTX) moves via
//     RELAXED agent-scope atomics (coherent at LLC, no L2 flush/inv); barrier
//     is relaxed flag store + poll. Agent acq/rel cache maintenance (L2
//     writeback+invalidate per barrier, 1200x) is eliminated; weights stay
//     L2-resident across all steps. Ordering: __syncthreads drains vmcnt
//     before flag store; poll -> barrier -> loads in program order.
//  2) ILP/vectorization: phase A = (kq4 x row16 x colpair16) float2 weight
//     loads, K-chain halved, n-gate x/h parts reduced separately; B2 cat =
//     4-way split-K float2; B1 history loads float4 (1KB/wave/instr).
// ---------------------------------------------------------------------------

#define TT 400
#define BB 256
#define HH 256
#define XEc 32
#define NXc 100
#define SEc 16
#define G3 768
#define KXc 289   // XE + H + 1

#define AGT __HIP_MEMORY_SCOPE_AGENT
#define RLX __ATOMIC_RELAXED

// workspace offsets (floats)
constexpr size_t XEMB_O     = 0;
constexpr size_t FBUF_O     = XEMB_O     + (size_t)TT*BB*XEc;   // [b][t][h]
constexpr size_t CFBUF_O    = FBUF_O     + (size_t)BB*TT*HH;
constexpr size_t FHX_O      = CFBUF_O    + (size_t)BB*TT*HH;    // [2][b][h]
constexpr size_t CFHX_O     = FHX_O      + (size_t)2*BB*HH;
constexpr size_t FOLD_O     = CFHX_O     + (size_t)2*BB*HH;
constexpr size_t CFOLD_O    = FOLD_O     + (size_t)2*BB*HH;
constexpr size_t CTXF_O     = CFOLD_O    + (size_t)2*BB*HH;
constexpr size_t CTXCF_O    = CTXF_O     + (size_t)BB*HH;
constexpr size_t DEMO_O     = CTXCF_O    + (size_t)BB*HH;
constexpr size_t DEMOIPW_O  = DEMO_O     + (size_t)BB*SEc;
constexpr size_t TRF_O      = DEMOIPW_O  + (size_t)BB*HH;
constexpr size_t XEMBMAX_O  = TRF_O      + (size_t)BB;
constexpr size_t FOLDMAX_O  = XEMBMAX_O  + (size_t)BB*XEc;
constexpr size_t CFOLDMAX_O = FOLDMAX_O  + (size_t)BB*HH;
constexpr size_t BAR_O      = CFOLDMAX_O + (size_t)BB*HH;
constexpr int    BAR_WORDS  = 4096;     // flags[256] @ 16-word (64B) stride

// out offsets (floats)
constexpr size_t IPW_OUT   = 0;          // (T,B,1)
constexpr size_t FOUT_OUT  = 102400;     // (B,1)
constexpr size_t CFOUT_OUT = 102656;     // (B,1)
constexpr size_t FH_OUT    = 102912;     // (B,256)

struct P {
  const float *x, *x_demo, *x_fr, *f_hx0, *cf_hx0;
  const float *w_x2emb, *b_x2emb, *w_static, *b_static;
  const float *wih_f, *whh_f, *bih_f, *bhh_f;
  const float *wih_cf, *whh_cf, *bih_cf, *bhh_cf;
  const float *w_cat_f, *b_cat_f, *w_cat_cf, *b_cat_cf;
  const float *w_ipw, *b_ipw, *w_ipw_out;
  const float *w_of, *b_of, *w_ho_f;
  const float *w_ocf, *b_ocf, *w_ho_cf;
  float *out; float *ws;
};

__device__ __forceinline__ float sigm(float v) { return 1.f / (1.f + expf(-v)); }

__device__ __forceinline__ float ald(const float* a) {
  return __hip_atomic_load(a, RLX, AGT);
}
__device__ __forceinline__ void ast(float* a, float v) {
  __hip_atomic_store(a, v, RLX, AGT);
}

// ---------------------------------------------------------------------------
// 16-WG group barrier, RELAXED flags (LLC-coherent; no L2 flush/inv).
// Writer side: all cross-WG data is written with relaxed AGENT atomics
// (acked at the LLC); __syncthreads() drains each wave's vmcnt before tid0
// stores the flag, so the flag can only be observed after the data is at the
// coherence point. Reader side: poll -> __syncthreads -> relaxed atomic data
// loads (program order, in-order vmem issue). Monotonic targets, no ABA.
// ---------------------------------------------------------------------------
__device__ __forceinline__ void gsyncg(float* ws, int wg, unsigned target) {
  __syncthreads();                      // drains vmcnt: data stores acked
  unsigned* flags = reinterpret_cast<unsigned*>(ws + BAR_O);
  const int tid = threadIdx.x;
  if (tid == 0)
    __hip_atomic_store(&flags[wg * 16], target, RLX, AGT);
  const int gbase = (wg & ~15) * 16;    // flag index of group's first member
  if (tid < 16) {
    while (__hip_atomic_load(&flags[gbase + tid * 16], RLX, AGT) < target)
      __builtin_amdgcn_s_sleep(8);
  }
  __syncthreads();
}

// ------------------------- pre kernels -------------------------------------
__global__ __launch_bounds__(256) void preA_k(P p) {
  __shared__ float wle[NXc * XEc];      // [f][e]
  __shared__ float xt[64 * NXc];        // 64 x rows staged
  float* ws = p.ws;
  const int t = blockIdx.x;
  for (int i = threadIdx.x; i < NXc * XEc; i += 256) wle[i] = p.w_x2emb[i];
  const int e = threadIdx.x & 31, r0 = threadIdx.x >> 5;
  for (int bt = 0; bt < 4; ++bt) {
    __syncthreads();
    for (int i = threadIdx.x; i < 64 * NXc; i += 256) {
      int r = i / NXc, f = i - r * NXc;
      xt[i] = p.x[((size_t)(bt * 64 + r) * TT + t) * NXc + f];
    }
    __syncthreads();
    for (int r = r0; r < 64; r += 8) {
      const float* xr = xt + r * NXc;
      float acc = p.b_x2emb[e];
      for (int f = 0; f < NXc; ++f) acc += xr[f] * wle[f * XEc + e];
      ws[XEMB_O + ((size_t)t * BB + bt * 64 + r) * XEc + e] = acc;
    }
  }
}

__global__ __launch_bounds__(256) void preB_k(P p) {
  float* ws = p.ws;
  const int tid = threadIdx.x;
  const int blk = blockIdx.x;
  if (blk < 32) {                       // xemb running max over t
    int g = blk * 256 + tid;            // g = b*32+e
    int b = g >> 5, e = g & 31;
    float m = -3.4e38f;
    for (int t = 0; t < TT; ++t)
      m = fmaxf(m, ws[XEMB_O + ((size_t)t * BB + b) * XEc + e]);
    ws[XEMBMAX_O + g] = m;
  } else if (blk < 64) {                // zero atomically-updated out regions
    int g = (blk - 32) * 256 + tid;
    for (size_t i = g; i < 102912; i += 8192) p.out[i] = 0.f;
  } else if (blk == 64) {               // demo = x_demo @ w_static + b_static
    for (int i = tid; i < BB * SEc; i += 256) {
      int b = i >> 4, se = i & 15;
      float acc = p.b_static[se];
      for (int ns = 0; ns < 5; ++ns) acc += p.x_demo[b * 5 + ns] * p.w_static[ns * SEc + se];
      ws[DEMO_O + i] = acc;
    }
  } else if (blk < 81) {                // demo_ipw[b][j] = demo(b) @ w_ipw[288:304]
    int g = (blk - 65) * 256 + tid;
    for (int i = g; i < BB * HH; i += 4096) {
      int b = i >> 8, j = i & 255;
      float acc = 0.f;
      for (int se = 0; se < SEc; ++se) {
        float d = p.b_static[se];
        for (int ns = 0; ns < 5; ++ns) d += p.x_demo[b * 5 + ns] * p.w_static[ns * SEc + se];
        acc += d * p.w_ipw[(size_t)(288 + se) * HH + j];
      }
      ws[DEMOIPW_O + i] = acc;
    }
  } else if (blk == 81) {               // f_tr flag per b
    int b = tid;
    float s = 0.f;
    for (int t = 0; t < TT; ++t) s += p.x_fr[(size_t)b * TT + t];
    ws[TRF_O + b] = (s > 0.f) ? 1.f : 0.f;
  } else if (blk < 98) {                // state inits + running-max inits
    int g = (blk - 82) * 256 + tid;
    for (int i = g; i < 6 * BB * HH; i += 4096) {
      int a = i >> 16, r = i & 65535;
      float vf = p.f_hx0[r], vc = p.cf_hx0[r];
      size_t off; float v;
      switch (a) {
        case 0: off = FHX_O;      v = vf; break;
        case 1: off = CFHX_O;     v = vc; break;
        case 2: off = FOLD_O;     v = vf; break;
        case 3: off = CFOLD_O;    v = vc; break;
        case 4: off = FOLDMAX_O;  v = vf; break;
        default: off = CFOLDMAX_O; v = vc; break;
      }
      ws[off + r] = v;
    }
  } else if (blk == 98) {               // zero barrier flag region
    unsigned* bw = reinterpret_cast<unsigned*>(ws + BAR_O);
    for (int i = tid; i < BAR_WORDS; i += 256) bw[i] = 0u;
  }
}

// ------------------------- persistent sequential kernel --------------------
// LDS layout (floats), unioned per phase (max 14368 = 57.5 KB):
//  A : ax[16][290] @0 (4640) | ah[16][257] @4640 (4112) | red[3*1536] @8752
//  B1: q[256] @0 | cm[16] @256 | cs[16] @272 | cc[16*256] @288
//  B2: ct[16][513] @0 (8208) | it[16][289] @8208 (4624) | red2[3*512] @12832
__global__ __launch_bounds__(1024) void seq_k(P p) {
  __shared__ float lds[14368];
  float* ws = p.ws;
  const int tid = threadIdx.x;
  const int wg = blockIdx.x;
  const int btile = wg >> 4, slice = wg & 15;
  const int cell = slice >> 3, sl = slice & 7;
  const int b0 = btile * 16;
  // GEMM mapping (phases A and B2): kq x row x col-pair
  const int gcp = tid & 15;             // col-pair
  const int gr  = (tid >> 4) & 15;      // row in btile
  const int kq  = tid >> 8;             // 0..3 k-split
  const int jo  = sl * 32 + gcp * 2;    // first of 2 output columns

  unsigned tgt = 1;                     // monotonic barrier target

  for (int t = 0; t < TT; ++t) {
    const int rd = t & 1, wr = 1 - rd;

    // ---------------- phase A: GRU gates GEMM + elementwise update ---------
    {
      float* ax  = lds;                 // [16][290], 289 used
      float* ah  = lds + 4640;          // [16][257], 256 used
      float* red = lds + 8752;          // [3][1536]
      const float* oldv = ws + (cell ? CFOLD_O : FOLD_O) + (size_t)rd * BB * HH;
      const float* hxv  = ws + (cell ? CFHX_O  : FHX_O ) + (size_t)rd * BB * HH;
      float*       hxn  = ws + (cell ? CFHX_O  : FHX_O ) + (size_t)wr * BB * HH;

      for (int i = tid; i < 16 * KXc; i += 1024) {
        int r = i / KXc, k = i - r * KXc; int b = b0 + r; float v;
        if (k < XEc)            v = ws[XEMB_O + ((size_t)t * BB + b) * XEc + k];
        else if (k < XEc + HH)  v = ald(&oldv[(size_t)b * HH + (k - XEc)]);
        else                    v = cell ? (1.0f - ws[TRF_O + b]) : p.x_fr[(size_t)b * TT + t];
        ax[r * 290 + k] = v;
      }
      for (int i = tid; i < 16 * 256; i += 1024) {
        int r = i >> 8, k = i & 255;
        ah[r * 257 + k] = ald(&hxv[(size_t)(b0 + r) * HH + k]);
      }
      __syncthreads();

      float g0=0,g1=0,g2=0,g3=0,g4=0,g5=0;   // (r,z,n) x 2 cols partials
      if (kq < 2) {                          // x-part, K=289 split in two
        const int kbeg = (kq & 1) ? 145 : 0, kend = (kq & 1) ? 289 : 145;
        const float* a  = ax + gr * 290;
        const float* wk = (cell ? p.wih_cf : p.wih_f) + (size_t)kbeg * G3 + jo;
        #pragma unroll 8
        for (int k = kbeg; k < kend; ++k) {
          float av = a[k];
          float2 w0 = *(const float2*)(wk);
          float2 w1 = *(const float2*)(wk + 256);
          float2 w2 = *(const float2*)(wk + 512);
          g0 += av*w0.x; g1 += av*w0.y;
          g2 += av*w1.x; g3 += av*w1.y;
          g4 += av*w2.x; g5 += av*w2.y;
          wk += G3;
        }
      } else {                               // h-part, K=256 split in two
        const int kbeg = (kq & 1) ? 128 : 0, kend = kbeg + 128;
        const float* a  = ah + gr * 257;
        const float* wk = (cell ? p.whh_cf : p.whh_f) + (size_t)kbeg * G3 + jo;
        #pragma unroll 8
        for (int k = kbeg; k < kend; ++k) {
          float av = a[k];
          float2 w0 = *(const float2*)(wk);
          float2 w1 = *(const float2*)(wk + 256);
          float2 w2 = *(const float2*)(wk + 512);
          g0 += av*w0.x; g1 += av*w0.y;
          g2 += av*w1.x; g3 += av*w1.y;
          g4 += av*w2.x; g5 += av*w2.y;
          wk += G3;
        }
      }
      if (kq != 0) {
        float* rp = red + (size_t)(kq - 1) * 1536 + (gr * 16 + gcp) * 6;
        rp[0]=g0; rp[1]=g1; rp[2]=g2; rp[3]=g3; rp[4]=g4; rp[5]=g5;
      }
      __syncthreads();
      if (kq == 0) {
        const float* bih = cell ? p.bih_cf : p.bih_f;
        const float* bhh = cell ? p.bhh_cf : p.bhh_f;
        const float* r1 = red +        (gr * 16 + gcp) * 6;   // x-part tail
        const float* r2 = red + 1536 + (gr * 16 + gcp) * 6;   // h-part lo
        const float* r3 = red + 3072 + (gr * 16 + gcp) * 6;   // h-part hi
        int b = b0 + gr;
        // col 0
        {
          int j = jo;
          float xr = g0 + r1[0], xz = g2 + r1[2], xn = g4 + r1[4];
          float hr = r2[0] + r3[0], hz = r2[2] + r3[2], hn = r2[4] + r3[4];
          float hprev = ah[gr * 257 + j];
          float rr = sigm(xr + bih[j]       + hr + bhh[j]);
          float zz = sigm(xz + bih[j + 256] + hz + bhh[j + 256]);
          float nn = tanhf(xn + bih[j + 512] + rr * (hn + bhh[j + 512]));
          ast(&hxn[(size_t)b * HH + j], (1.f - zz) * nn + zz * hprev);
        }
        // col 1
        {
          int j = jo + 1;
          float xr = g1 + r1[1], xz = g3 + r1[3], xn = g5 + r1[5];
          float hr = r2[1] + r3[1], hz = r2[3] + r3[3], hn = r2[5] + r3[5];
          float hprev = ah[gr * 257 + j];
          float rr = sigm(xr + bih[j]       + hr + bhh[j]);
          float zz = sigm(xz + bih[j + 256] + hz + bhh[j + 256]);
          float nn = tanhf(xn + bih[j + 512] + rr * (hn + bhh[j + 512]));
          ast(&hxn[(size_t)b * HH + j], (1.f - zz) * nn + zz * hprev);
        }
      }
    }
    gsyncg(ws, wg, tgt++);

    // ---------------- phase B1: per-b flash attention + history append ----
    {
      const int b = wg;
      for (int c = 0; c < 2; ++c) {
        const float* hnew = ws + (c ? CFHX_O : FHX_O) + (size_t)wr * BB * HH + (size_t)b * HH;
        float* buf = ws + (c ? CFBUF_O : FBUF_O) + (size_t)b * TT * HH;
        float* ctx = ws + (c ? CTXCF_O : CTXF_O) + (size_t)b * HH;
        float* q = lds;                 // [256]
        if (tid < 256) {
          float v = ald(&hnew[tid]);
          q[tid] = v;
          buf[(size_t)t * HH + tid] = v;   // self-read only: normal store
        }
        __syncthreads();
        if (t == 0) {
          if (tid < 256) ast(&ctx[tid], q[tid]);
          __syncthreads();
        } else {
          const int wv = tid >> 6, ln = tid & 63;
          const float4 qv = *(const float4*)&q[4 * ln];
          float m = -1e30f, ssum = 0.f, c0 = 0.f, c1 = 0.f, c2 = 0.f, c3 = 0.f;
          int tp = wv;
          for (; tp + 16 < t; tp += 32) {     // 2-row unroll (rows tp, tp+16)
            const float4 a = *(const float4*)(buf + (size_t)tp * HH + 4 * ln);
            const float4 e = *(const float4*)(buf + (size_t)(tp + 16) * HH + 4 * ln);
            float da = a.x*qv.x + a.y*qv.y + a.z*qv.z + a.w*qv.w;
            float db = e.x*qv.x + e.y*qv.y + e.z*qv.z + e.w*qv.w;
            #pragma unroll
            for (int off = 32; off; off >>= 1) {
              da += __shfl_xor(da, off, 64);
              db += __shfl_xor(db, off, 64);
            }
            float nm = fmaxf(m, fmaxf(da, db));
            float al = expf(m - nm), pa = expf(da - nm), pb = expf(db - nm);
            ssum = ssum * al + pa + pb;
            c0 = c0 * al + pa * a.x + pb * e.x;
            c1 = c1 * al + pa * a.y + pb * e.y;
            c2 = c2 * al + pa * a.z + pb * e.z;
            c3 = c3 * al + pa * a.w + pb * e.w;
            m = nm;
          }
          if (tp < t) {                        // tail row
            const float4 a = *(const float4*)(buf + (size_t)tp * HH + 4 * ln);
            float d = a.x*qv.x + a.y*qv.y + a.z*qv.z + a.w*qv.w;
            #pragma unroll
            for (int off = 32; off; off >>= 1) d += __shfl_xor(d, off, 64);
            float nm = fmaxf(m, d);
            float al = expf(m - nm), pv = expf(d - nm);
            ssum = ssum * al + pv;
            c0 = c0 * al + pv * a.x; c1 = c1 * al + pv * a.y;
            c2 = c2 * al + pv * a.z; c3 = c3 * al + pv * a.w;
            m = nm;
          }
          float* cm = lds + 256; float* cs = lds + 272; float* cc = lds + 288;
          if (ln == 0) { cm[wv] = m; cs[wv] = ssum; }
          *(float4*)&cc[wv * 256 + 4 * ln] = make_float4(c0, c1, c2, c3);
          __syncthreads();
          if (tid < 256) {
            float M = cm[0];
            #pragma unroll
            for (int w2 = 1; w2 < 16; ++w2) M = fmaxf(M, cm[w2]);
            float S = 0.f, num = 0.f;
            #pragma unroll
            for (int w2 = 0; w2 < 16; ++w2) {
              float e = expf(cm[w2] - M);
              S   += cs[w2] * e;
              num += cc[w2 * 256 + tid] * e;
            }
            ast(&ctx[tid], num / S);
          }
          __syncthreads();
        }
      }
    }
    gsyncg(ws, wg, tgt++);

    // ---------------- phase B2: cat GEMM + maxes + IPW head ----------------
    {
      float* ct   = lds;                // [16][513], 512 used
      float* it   = lds + 8208;         // [16][289], 288 used
      float* red2 = lds + 12832;        // [3][512]
      const float* hnew = ws + (cell ? CFHX_O : FHX_O) + (size_t)wr * BB * HH;
      const float* ctxv = ws + (cell ? CTXCF_O : CTXF_O);
      const float* oldr = ws + FOLD_O + (size_t)rd * BB * HH;
      for (int i = tid; i < 16 * 512; i += 1024) {
        int r = i >> 9, k = i & 511; int b = b0 + r;
        ct[r * 513 + k] = (k < 256) ? ald(&hnew[(size_t)b * HH + k])
                                    : ald(&ctxv[(size_t)b * HH + (k - 256)]);
      }
      for (int i = tid; i < 16 * 288; i += 1024) {
        int r = i / 288, k = i - r * 288; int b = b0 + r;
        it[r * 289 + k] = (k < 32) ? ws[XEMB_O + ((size_t)t * BB + b) * XEc + k]
                                   : ald(&oldr[(size_t)b * HH + (k - 32)]);
      }
      __syncthreads();

      // cat GEMM, split-K 4-way, float2 columns
      {
        const float* wc = cell ? p.w_cat_cf : p.w_cat_f;
        float a0 = 0.f, a1 = 0.f;
        const float* ar = ct + gr * 513 + kq * 128;
        const float* wp = wc + (size_t)(kq * 128) * HH + jo;
        #pragma unroll 8
        for (int k = 0; k < 128; ++k) {
          float av = ar[k];
          float2 w = *(const float2*)(wp);
          a0 += av * w.x; a1 += av * w.y;
          wp += HH;
        }
        if (kq != 0) {
          float* rp = red2 + (kq - 1) * 512 + (gr * 16 + gcp) * 2;
          rp[0] = a0; rp[1] = a1;
        }
        __syncthreads();
        if (kq == 0) {
          const float* bc = cell ? p.b_cat_cf : p.b_cat_f;
          const float* r1 = red2 +        (gr * 16 + gcp) * 2;
          const float* r2 = red2 + 512  + (gr * 16 + gcp) * 2;
          const float* r3 = red2 + 1024 + (gr * 16 + gcp) * 2;
          int b = b0 + gr;
          float f0 = tanhf(a0 + r1[0] + r2[0] + r3[0] + bc[jo]);
          float f1 = tanhf(a1 + r1[1] + r2[1] + r3[1] + bc[jo + 1]);
          float* on = ws + (cell ? CFOLD_O : FOLD_O) + (size_t)wr * BB * HH;
          ast(&on[(size_t)b * HH + jo],     f0);
          ast(&on[(size_t)b * HH + jo + 1], f1);
          if (t < TT - 1) {               // f_old(t) enters f_zx only for t<=T-2
            float* fm = ws + (cell ? CFOLDMAX_O : FOLDMAX_O);
            fm[(size_t)b * HH + jo]     = fmaxf(fm[(size_t)b * HH + jo], f0);
            fm[(size_t)b * HH + jo + 1] = fmaxf(fm[(size_t)b * HH + jo + 1], f1);
          }
        }
      }
      // IPW head: relu([x_emb, f_old(t-1), demo] @ w_ipw + b) @ w_ipw_out
      {
        const int ir = tid >> 6, il = tid & 63;
        const int itj = il >> 2, ikq = il & 3;    // 16 cols x 4 k-quarters
        const int cI = slice * 16 + itj;
        const int b = b0 + ir;
        float acc = 0.f;
        const float* itr = it + ir * 289;
        const float* wi = p.w_ipw + cI;
        #pragma unroll 4
        for (int k = ikq * 72; k < ikq * 72 + 72; ++k) acc += itr[k] * wi[(size_t)k * HH];
        acc += __shfl_xor(acc, 1, 64);
        acc += __shfl_xor(acc, 2, 64);
        float tot = acc + p.b_ipw[cI] + ws[DEMOIPW_O + (size_t)b * HH + cI];
        float pr = (tot > 0.f) ? tot * p.w_ipw_out[cI] : 0.f;
        pr += __shfl_xor(pr, 4, 64);
        pr += __shfl_xor(pr, 8, 64);
        pr += __shfl_xor(pr, 16, 64);
        pr += __shfl_xor(pr, 32, 64);
        if (il == 0) atomicAdd(p.out + IPW_OUT + (size_t)t * BB + b, pr);
      }
    }
    gsyncg(ws, wg, tgt++);
  }
}

// ------------------------- post kernel: output heads -----------------------
__global__ __launch_bounds__(256) void post_k(P p) {
  __shared__ float at[16 * 306];
  float* ws = p.ws;
  const int tid = threadIdx.x;
  const int wg = blockIdx.x;
  const int btile = wg >> 4, slice = wg & 15;
  const int cell = slice >> 3, sl = slice & 7;
  const int b0 = btile * 16;
  const int tb = tid >> 4, tj = tid & 15;

  for (int i = tid; i < 16 * 305; i += 256) {
    int r = i / 305, k = i - r * 305; int b = b0 + r; float v;
    if (k < 32)        v = ws[XEMBMAX_O + (size_t)b * XEc + k];
    else if (k < 288)  v = ws[(cell ? CFOLDMAX_O : FOLDMAX_O) + (size_t)b * HH + (k - 32)];
    else if (k < 304)  v = ws[DEMO_O + (size_t)b * SEc + (k - 288)];
    else { float tr = ws[TRF_O + b]; v = cell ? (1.f - tr) : tr; }
    at[r * 306 + k] = v;
  }
  __syncthreads();

  const int jo = sl * 32 + tj * 2;
  const float* wo  = cell ? p.w_ocf   : p.w_of;
  const float* bo  = cell ? p.b_ocf   : p.b_of;
  const float* who = cell ? p.w_ho_cf : p.w_ho_f;
  float a0 = 0.f, a1 = 0.f;
  const float* ar = at + tb * 306;
  const float* wop = wo + jo;
  for (int k = 0; k < 305; ++k) {
    float a = ar[k];
    float2 w = *(const float2*)(wop + (size_t)k * HH);
    a0 += a * w.x; a1 += a * w.y;
  }
  int b = b0 + tb;
  float h0 = fmaxf(a0 + bo[jo], 0.f), h1 = fmaxf(a1 + bo[jo + 1], 0.f);
  if (!cell) {
    p.out[FH_OUT + (size_t)b * HH + jo]     = h0;
    p.out[FH_OUT + (size_t)b * HH + jo + 1] = h1;
  }
  float pr = h0 * who[jo] + h1 * who[jo + 1];
  pr += __shfl_xor(pr, 8, 16);
  pr += __shfl_xor(pr, 4, 16);
  pr += __shfl_xor(pr, 2, 16);
  pr += __shfl_xor(pr, 1, 16);
  if (tj == 0) atomicAdd(p.out + (cell ? CFOUT_OUT : FOUT_OUT) + b, pr);
}

// ---------------------------------------------------------------------------
extern "C" void kernel_launch(void* const* d_in, const int* in_sizes, int n_in,
                              void* d_out, int out_size, void* d_ws, size_t ws_size,
                              hipStream_t stream) {
  (void)in_sizes; (void)n_in; (void)out_size; (void)ws_size;
  P p;
  p.x        = (const float*)d_in[0];
  p.x_demo   = (const float*)d_in[1];
  p.x_fr     = (const float*)d_in[2];
  p.f_hx0    = (const float*)d_in[3];
  p.cf_hx0   = (const float*)d_in[4];
  p.w_x2emb  = (const float*)d_in[5];
  p.b_x2emb  = (const float*)d_in[6];
  p.w_static = (const float*)d_in[7];
  p.b_static = (const float*)d_in[8];
  p.wih_f    = (const float*)d_in[9];
  p.whh_f    = (const float*)d_in[10];
  p.bih_f    = (const float*)d_in[11];
  p.bhh_f    = (const float*)d_in[12];
  p.wih_cf   = (const float*)d_in[13];
  p.whh_cf   = (const float*)d_in[14];
  p.bih_cf   = (const float*)d_in[15];
  p.bhh_cf   = (const float*)d_in[16];
  p.w_cat_f  = (const float*)d_in[17];
  p.b_cat_f  = (const float*)d_in[18];
  p.w_cat_cf = (const float*)d_in[19];
  p.b_cat_cf = (const float*)d_in[20];
  p.w_ipw    = (const float*)d_in[21];
  p.b_ipw    = (const float*)d_in[22];
  p.w_ipw_out= (const float*)d_in[23];
  p.w_of     = (const float*)d_in[24];
  p.b_of     = (const float*)d_in[25];
  p.w_ho_f   = (const float*)d_in[26];
  p.w_ocf    = (const float*)d_in[27];
  p.b_ocf    = (const float*)d_in[28];
  p.w_ho_cf  = (const float*)d_in[29];
  p.out = (float*)d_out;
  p.ws  = (float*)d_ws;

  preA_k<<<dim3(TT), dim3(256), 0, stream>>>(p);
  preB_k<<<dim3(256), dim3(256), 0, stream>>>(p);

  void* kp[] = { &p };
  hipLaunchCooperativeKernel((const void*)seq_k, dim3(256), dim3(1024), kp, 0, stream);

  post_k<<<dim3(256), dim3(256), 0, stream>>>(p);
}